// Round 9
// baseline (782.196 us; speedup 1.0000x reference)
//
#include <hip/hip_runtime.h>
#include <hip/hip_bf16.h>

#define NB    15
#define NMC   10000
#define NTR   20000
#define NTE   10000
#define BSZ   1024
#define NCLS  10
#define NQ_ALL (NB * NMC)

// KDE constants: BW=0.3, KDE_NORM = 2*pi*BW*BW
#define KDE_NORM  0.5654866776461628f
#define EXPC      8.014972449383130f    /* log2(e)/0.18 */
#define TWO_EXPC  16.029944898766260f   /* 2*EXPC */
#define LOG2E     1.4426950408889634f

// spatial grid: 12x12 unit cells over [-6,6]^2. 5x5 box => dropped pairs have
// gap >= 2.0 -> k <= exp(-22.2) = 2.2e-10; error ~1e-8 after norm.
#define GX      12
#define NCELL   144
#define CELL_LO -6.0f

// ---------------- pruned-path ws layout (same as R8) ----------------------
#define MC_ST  64
#define TR_ST  224
#define TE_ST  384
#define BX_ST  544
#define MC_CUR 704
#define TR_CUR 864
#define TE_CUR 1024
#define BX_CUR 1184
#define P_PR   1344
#define PR_ZERO_FLOATS (P_PR + 3 * NQ_ALL)
#define MCS_B   (PR_ZERO_FLOATS * 4)
#define TRS_B   (MCS_B + NQ_ALL * 16)
#define TES_B   (TRS_B + NTR * 16)
#define BXS_B   (TES_B + NTE * 16)
#define PR_NEED (BXS_B + BSZ * 16)

#define QCH    3       /* q-chunks of 512 (2 q per thread) */
#define SLICES 10      /* data slices for tr/te; batch rows on slices 0..4 */

// ---------------- mid-path (R5) layout ------------------------------------
#define CW_OFF   64
#define P_MID    1088
#define WS_MID_FLOATS (P_MID + 3 * NQ_ALL)
#define MDS   17
#define MTILE 256
#define MMQ   8

// ---------------- fallback path -------------------------------------------
#define WS_SMALL 1088
#define FTILE 256

typedef float v2f __attribute__((ext_vector_type(2)));

__device__ __forceinline__ float fast_exp2(float x) {
#if __has_builtin(__builtin_amdgcn_exp2f)
    return __builtin_amdgcn_exp2f(x);
#else
    return exp2f(x);
#endif
}

__device__ __forceinline__ int cell_of(float x, float y) {
    int ix = (int)floorf(x - CELL_LO);
    ix = min(max(ix, 0), GX - 1);
    int iy = (int)floorf(y - CELL_LO);
    iy = min(max(iy, 0), GX - 1);
    return iy * GX + ix;
}

// ---------------------------------------------------------------- setup ----
__global__ void setup_k(const int* __restrict__ by, const int* __restrict__ bp,
                        const float* __restrict__ trp, const float* __restrict__ tep,
                        float* __restrict__ ws, int write_cw)
{
    int i    = blockIdx.x * blockDim.x + threadIdx.x;
    int lane = threadIdx.x & 63;

    float c = 0.f;
    if (i < BSZ) {
        c = (by[i] == bp[i]) ? 1.f : 0.f;
        if (write_cw) ws[CW_OFF + i] = c;
    }
    unsigned long long mc = __ballot(c != 0.f);
    if (lane == 0 && mc) atomicAdd(&ws[0], (float)__popcll(mc));

    float p_tr = (i < NTR) ? trp[i] : -1.f;
    float p_te = (i < NTE) ? tep[i] : -1.f;
    const float step = 1.0f / 15.0f;
    for (int b2 = 0; b2 < NB; b2++) {
        float lo = b2 * step;
        float hi = (b2 == NB - 1) ? 1.0f : (b2 + 1) * step;
        unsigned long long m1 = __ballot(p_tr > lo && p_tr <= hi);
        unsigned long long m2 = __ballot(p_te > lo && p_te <= hi);
        if (lane == 0) {
            if (m1) atomicAdd(&ws[1  + b2], (float)__popcll(m1));
            if (m2) atomicAdd(&ws[16 + b2], (float)__popcll(m2));
        }
    }
}

// ------------------------------------------------------- counting sort ----
__global__ void count_k(const float2* __restrict__ bx, const float2* __restrict__ tr,
                        const float2* __restrict__ te, const float2* __restrict__ mc,
                        int* __restrict__ W)
{
    int i = blockIdx.x * blockDim.x + threadIdx.x;
    if (i < BSZ) { float2 p = bx[i]; atomicAdd(&W[BX_ST + 1 + cell_of(p.x, p.y)], 1); }
    if (i < NTE) { float2 p = te[i]; atomicAdd(&W[TE_ST + 1 + cell_of(p.x, p.y)], 1); }
    if (i < NTR) { float2 p = tr[i]; atomicAdd(&W[TR_ST + 1 + cell_of(p.x, p.y)], 1); }
    if (i < NQ_ALL) { float2 p = mc[i]; atomicAdd(&W[MC_ST + 1 + cell_of(p.x, p.y)], 1); }
}

// Parallel LDS scan (R8's serial global chain was ~25us).
__global__ void scan_k(int* __restrict__ W)
{
    __shared__ int buf[NCELL];
    int tid = threadIdx.x;   // 256
#pragma unroll
    for (int t = 0; t < 4; ++t) {
        int st  = (t == 0) ? MC_ST  : (t == 1) ? TR_ST  : (t == 2) ? TE_ST  : BX_ST;
        int cur = (t == 0) ? MC_CUR : (t == 1) ? TR_CUR : (t == 2) ? TE_CUR : BX_CUR;
        int v = 0;
        if (tid < NCELL) { v = W[st + 1 + tid]; buf[tid] = v; }
        __syncthreads();
        for (int off = 1; off < NCELL; off <<= 1) {
            int x = 0;
            if (tid < NCELL && tid >= off) x = buf[tid - off];
            __syncthreads();
            if (tid < NCELL) buf[tid] += x;
            __syncthreads();
        }
        if (tid < NCELL) {
            int start = buf[tid] - v;          // exclusive
            W[st  + tid] = start;
            W[cur + tid] = start;
            if (tid == NCELL - 1) W[st + NCELL] = buf[tid];
        }
        __syncthreads();
    }
}

__global__ void scatter_k(const float2* __restrict__ bx,
                          const int* __restrict__ by, const int* __restrict__ bp,
                          const float2* __restrict__ tr, const float2* __restrict__ te,
                          const float2* __restrict__ mc,
                          int* __restrict__ W,
                          float4* __restrict__ bxS, float4* __restrict__ trS,
                          float4* __restrict__ teS, float4* __restrict__ mcS)
{
    int i = blockIdx.x * blockDim.x + threadIdx.x;
    if (i < BSZ) {
        float2 p = bx[i];
        int pos = atomicAdd(&W[BX_CUR + cell_of(p.x, p.y)], 1);
        float w = (by[i] == bp[i]) ? 1.f : 0.f;
        bxS[pos] = make_float4(TWO_EXPC * p.x, TWO_EXPC * p.y,
                               -EXPC * fmaf(p.x, p.x, p.y * p.y), w);
    }
    if (i < NTE) {
        float2 p = te[i];
        int pos = atomicAdd(&W[TE_CUR + cell_of(p.x, p.y)], 1);
        teS[pos] = make_float4(TWO_EXPC * p.x, TWO_EXPC * p.y,
                               -EXPC * fmaf(p.x, p.x, p.y * p.y), 1.f);
    }
    if (i < NTR) {
        float2 p = tr[i];
        int pos = atomicAdd(&W[TR_CUR + cell_of(p.x, p.y)], 1);
        trS[pos] = make_float4(TWO_EXPC * p.x, TWO_EXPC * p.y,
                               -EXPC * fmaf(p.x, p.x, p.y * p.y), 1.f);
    }
    if (i < NQ_ALL) {
        float2 p = mc[i];
        int pos = atomicAdd(&W[MC_CUR + cell_of(p.x, p.y)], 1);
        mcS[pos] = make_float4(p.x, p.y,
                               -EXPC * fmaf(p.x, p.x, p.y * p.y),
                               (float)(i / NMC));
    }
}

// ------------------------------------------------------------- main KDE ----
// Block = (cell, q-chunk-of-512, slice). Each thread owns TWO q (tid, tid+256)
// -> each staged LDS point amortized over 2 pairs (halves ds_read + loop
// overhead around the ~1/8-rate v_exp floor). Batch rows are distributed one
// per slice (slices 0..rows-1) instead of all on slice 0.
__global__ __launch_bounds__(256) void main_k(
    const int*    __restrict__ W,
    const float4* __restrict__ mcS,
    const float4* __restrict__ trS,
    const float4* __restrict__ teS,
    const float4* __restrict__ bxS,
    float* __restrict__ P)
{
    __shared__ float4 tile[256];

    int tid   = threadIdx.x;
    int cell  = blockIdx.x;
    int chunk = blockIdx.y;
    int slice = blockIdx.z;

    int qs   = W[MC_ST + cell];
    int qend = W[MC_ST + cell + 1];
    if (qs >= qend) return;                       // uniform: whole block exits
    int ci = cell % GX, cj = cell / GX;
    int dj0 = max(cj - 2, 0), dj1 = min(cj + 2, GX - 1);
    int di0 = max(ci - 2, 0), di1 = min(ci + 2, GX - 1);
    int nrows = dj1 - dj0;                        // rows-1

    for (int q0 = qs + chunk * 512; q0 < qend; q0 += QCH * 512) {
        int  qa = q0 + tid;
        int  qb = q0 + 256 + tid;
        bool va = qa < qend, vb = qb < qend;
        float4 A = mcS[va ? qa : qs];
        float4 B = mcS[vb ? qb : qs];

        float a0 = 0.f, a1 = 0.f, a2 = 0.f;
        float b0 = 0.f, b1 = 0.f, b2 = 0.f;

#pragma unroll
        for (int ds = 0; ds < 2; ++ds) {          // train / test, sliced
            const float4* D  = ds ? teS : trS;
            const int*    St = W + (ds ? TE_ST : TR_ST);
            float accA = 0.f, accB = 0.f;
            for (int dj = dj0; dj <= dj1; ++dj) {
                int s0  = St[dj * GX + di0];
                int s1  = St[dj * GX + di1 + 1];
                int len = s1 - s0;
                int ss  = s0 + (len * slice) / SLICES;
                int se  = s0 + (len * (slice + 1)) / SLICES;
                for (int t0 = ss; t0 < se; t0 += 256) {
                    __syncthreads();
                    int o = t0 + tid;
                    tile[tid] = (o < se) ? D[o]
                                         : make_float4(0.f, 0.f, -1e30f, 0.f);
                    __syncthreads();
                    int cnt = min(256, se - t0);
#pragma unroll 4
                    for (int j = 0; j < cnt; ++j) {
                        float4 d = tile[j];
                        float ea = fmaf(A.x, d.x, fmaf(A.y, d.y, d.z + A.z));
                        float eb = fmaf(B.x, d.x, fmaf(B.y, d.y, d.z + B.z));
                        accA += fast_exp2(ea);
                        accB += fast_exp2(eb);
                    }
                }
            }
            if (ds == 0) { a0 = accA; b0 = accB; }
            else         { a1 = accA; b1 = accB; }
        }

        bool doBx = (slice <= nrows);             // one batch row per slice
        if (doBx) {
            int dj = dj0 + slice;
            const int* St = W + BX_ST;
            int ss = St[dj * GX + di0];
            int se = St[dj * GX + di1 + 1];
            float accA = 0.f, accB = 0.f;
            for (int t0 = ss; t0 < se; t0 += 256) {
                __syncthreads();
                int o = t0 + tid;
                tile[tid] = (o < se) ? bxS[o]
                                     : make_float4(0.f, 0.f, -1e30f, 0.f);
                __syncthreads();
                int cnt = min(256, se - t0);
#pragma unroll 4
                for (int j = 0; j < cnt; ++j) {
                    float4 d = tile[j];
                    float ea = fmaf(A.x, d.x, fmaf(A.y, d.y, d.z + A.z));
                    float eb = fmaf(B.x, d.x, fmaf(B.y, d.y, d.z + B.z));
                    accA = fmaf(d.w, fast_exp2(ea), accA);
                    accB = fmaf(d.w, fast_exp2(eb), accB);
                }
            }
            a2 = accA; b2 = accB;
        }

        if (va) {
            atomicAdd(&P[qa], a0);
            atomicAdd(&P[NQ_ALL + qa], a1);
            if (doBx) atomicAdd(&P[2 * NQ_ALL + qa], a2);
        }
        if (vb) {
            atomicAdd(&P[qb], b0);
            atomicAdd(&P[NQ_ALL + qb], b1);
            if (doBx) atomicAdd(&P[2 * NQ_ALL + qb], b2);
        }
        __syncthreads();
    }
}

// ------------------------------------------------------------- combine ----
// 74 blocks x 1024 threads x 2 q: device-atomic count to the hot S1/S2 words
// drops 17.6k -> 2.2k (R8 post-mortem: contended same-address atomics were
// the hidden ~300us dispatch).
__global__ __launch_bounds__(1024) void combine_pr(
    const float4* __restrict__ mcS,
    const float*  __restrict__ Wm,
    const float*  __restrict__ bv,
    const float*  __restrict__ wsf,   // [0] = cnt
    const float*  __restrict__ P,
    float* __restrict__ S1, float* __restrict__ S2)
{
    __shared__ float sb1[NB], sb2[NB];
    int tid = threadIdx.x;
    if (tid < NB) { sb1[tid] = 0.f; sb2[tid] = 0.f; }
    __syncthreads();

#pragma unroll
    for (int rep = 0; rep < 2; ++rep) {
        int i = blockIdx.x * 2048 + rep * 1024 + tid;
        if (i < NQ_ALL) {
            float4 q4 = mcS[i];
            float qx = q4.x, qy = q4.y;
            int bin = (int)q4.w;
            float t_tr = P[i];
            float t_te = P[NQ_ALL + i];
            float t_w  = P[2 * NQ_ALL + i];

            float lmax = -1e30f;
            float l[NCLS];
#pragma unroll
            for (int c = 0; c < NCLS; ++c) {
                l[c] = fmaf(qx, Wm[c], fmaf(qy, Wm[NCLS + c], bv[c]));
                lmax = fmaxf(lmax, l[c]);
            }
            float sume = 0.f;
#pragma unroll
            for (int c = 0; c < NCLS; ++c) sume += fast_exp2((l[c] - lmax) * LOG2E);
            float hat_s = 1.0f / sume;

            const float step = 1.0f / 15.0f;
            float lo = bin * step;
            float hi = (bin == NB - 1) ? 1.0f : (bin + 1) * step;
            float ind = (hat_s >= lo && hat_s <= hi) ? 1.f : 0.f;

            float cnt    = wsf[0];
            float kde_tr = t_tr * (1.0f / (NTR * KDE_NORM));
            float kde_te = t_te * (1.0f / (NTE * KDE_NORM));
            float kw     = t_w / (fmaxf(cnt, 1.0f) * KDE_NORM);
            float p_y    = cnt * (1.0f / BSZ);
            float p_hs   = kw * p_y / (kde_tr + 1e-8f);
            p_hs = fminf(fmaxf(p_hs, 0.f), 1.f);

            float c1 = p_hs * ind * kde_te;
            float c2 = p_hs * ind * kde_tr;
            if (c1 != 0.f) atomicAdd(&sb1[bin], c1);
            if (c2 != 0.f) atomicAdd(&sb2[bin], c2);
        }
    }
    __syncthreads();
    if (tid < NB) {
        if (sb1[tid] != 0.f) atomicAdd(&S1[tid], sb1[tid]);
        if (sb2[tid] != 0.f) atomicAdd(&S2[tid], sb2[tid]);
    }
}

// ===================== MID path: R5 kernel =================================
template <bool W>
__device__ __forceinline__ void mid_phase(const float2* __restrict__ pts,
                                          const float* __restrict__ wgt,
                                          int N, int slice,
                                          float* sAB, float* sCW,
                                          const float* qx, const float* qy, const float* qe,
                                          v2f* acc, int tid)
{
    v2f qx2[MMQ], qy2[MMQ], qe2[MMQ];
#pragma unroll
    for (int k = 0; k < MMQ; ++k) {
        qx2[k] = v2f{qx[k], qx[k]};
        qy2[k] = v2f{qy[k], qy[k]};
        qe2[k] = v2f{qe[k], qe[k]};
        acc[k] = v2f{0.f, 0.f};
    }

    int L      = (N + MDS - 1) / MDS;
    int start  = slice * L;
    int len    = min(L, N - start);
    int rounds = (len + MTILE - 1) / MTILE;
    for (int r = 0; r < rounds; ++r) {
        __syncthreads();
        int o = r * MTILE + tid;
        float a = 0.f, b = 0.f, c = -1e30f, wv = 0.f;
        if (o < len) {
            float2 p = pts[start + o];
            a = TWO_EXPC * p.x;
            b = TWO_EXPC * p.y;
            c = -EXPC * fmaf(p.x, p.x, p.y * p.y);
            if (W) wv = wgt[start + o];
        }
        int g4 = 4 * (tid >> 1) + (tid & 1);
        sAB[g4] = a;  sAB[g4 + 2] = b;
        sCW[g4] = c;  sCW[g4 + 2] = wv;
        __syncthreads();

        int cnt = min(MTILE, len - r * MTILE);
        int ng  = (cnt + 1) >> 1;
        const float4* AB4 = (const float4*)sAB;
        const float4* CW4 = (const float4*)sCW;
        for (int g = 0; g < ng; ++g) {
            float4 AB = AB4[g];
            float4 CW = CW4[g];
            v2f a01; a01.x = AB.x; a01.y = AB.y;
            v2f b01; b01.x = AB.z; b01.y = AB.w;
            v2f c01; c01.x = CW.x; c01.y = CW.y;
            v2f w01; w01.x = CW.z; w01.y = CW.w;
#pragma unroll
            for (int k = 0; k < MMQ; ++k) {
                v2f t0, t1, e;
                asm("v_pk_add_f32 %0, %1, %2" : "=v"(t0) : "v"(c01), "v"(qe2[k]));
                asm("v_pk_fma_f32 %0, %1, %2, %3" : "=v"(t1) : "v"(b01), "v"(qy2[k]), "v"(t0));
                asm("v_pk_fma_f32 %0, %1, %2, %3" : "=v"(e) : "v"(a01), "v"(qx2[k]), "v"(t1));
                float k0 = fast_exp2(e.x);
                float k1 = fast_exp2(e.y);
                if (W) {
                    acc[k].x = fmaf(w01.x, k0, acc[k].x);
                    acc[k].y = fmaf(w01.y, k1, acc[k].y);
                } else {
                    acc[k].x += k0;
                    acc[k].y += k1;
                }
            }
        }
    }
}

__global__ __launch_bounds__(256) void kdeA_mid(
    const float2* __restrict__ mc2,
    const float2* __restrict__ tr2,
    const float2* __restrict__ te2,
    const float2* __restrict__ bx2,
    const float*  __restrict__ ws,
    float* __restrict__ P)
{
    __shared__ float sAB[2 * MTILE];
    __shared__ float sCW[2 * MTILE];

    int tid   = threadIdx.x;
    int bin   = blockIdx.y;
    int slice = blockIdx.z;
    int base  = blockIdx.x * (256 * MMQ);

    int qi[MMQ];
    float qx[MMQ], qy[MMQ], qe[MMQ];
#pragma unroll
    for (int k = 0; k < MMQ; ++k) {
        qi[k] = base + k * 256 + tid;
        int qs = qi[k] < NMC ? qi[k] : (NMC - 1);
        float2 q = mc2[bin * NMC + qs];
        qx[k] = q.x;
        qy[k] = q.y;
        qe[k] = -EXPC * fmaf(q.x, q.x, q.y * q.y);
    }

    v2f acc[MMQ];

    mid_phase<false>(tr2, nullptr, NTR, slice, sAB, sCW, qx, qy, qe, acc, tid);
#pragma unroll
    for (int k = 0; k < MMQ; ++k)
        if (qi[k] < NMC) atomicAdd(&P[bin * NMC + qi[k]], acc[k].x + acc[k].y);

    mid_phase<false>(te2, nullptr, NTE, slice, sAB, sCW, qx, qy, qe, acc, tid);
#pragma unroll
    for (int k = 0; k < MMQ; ++k)
        if (qi[k] < NMC) atomicAdd(&P[NQ_ALL + bin * NMC + qi[k]], acc[k].x + acc[k].y);

    mid_phase<true>(bx2, ws + CW_OFF, BSZ, slice, sAB, sCW, qx, qy, qe, acc, tid);
#pragma unroll
    for (int k = 0; k < MMQ; ++k)
        if (qi[k] < NMC) atomicAdd(&P[2 * NQ_ALL + bin * NMC + qi[k]], acc[k].x + acc[k].y);
}

__global__ void combine_mid(const float2* __restrict__ mc2,
                            const float*  __restrict__ Wm,
                            const float*  __restrict__ bv,
                            const float*  __restrict__ ws,
                            const float*  __restrict__ P,
                            float* __restrict__ S1, float* __restrict__ S2)
{
    int bin  = blockIdx.y;
    int m    = blockIdx.x * 256 + threadIdx.x;
    int lane = threadIdx.x & 63;

    float c1 = 0.f, c2 = 0.f;
    if (m < NMC) {
        float2 q = mc2[bin * NMC + m];
        int idx  = bin * NMC + m;
        float t_tr = P[idx];
        float t_te = P[NQ_ALL + idx];
        float t_w  = P[2 * NQ_ALL + idx];

        float lmax = -1e30f;
        float l[NCLS];
#pragma unroll
        for (int c = 0; c < NCLS; ++c) {
            l[c] = fmaf(q.x, Wm[c], fmaf(q.y, Wm[NCLS + c], bv[c]));
            lmax = fmaxf(lmax, l[c]);
        }
        float sume = 0.f;
#pragma unroll
        for (int c = 0; c < NCLS; ++c) sume += expf(l[c] - lmax);
        float hat_s = 1.0f / sume;

        const float step = 1.0f / 15.0f;
        float lo = bin * step;
        float hi = (bin == NB - 1) ? 1.0f : (bin + 1) * step;
        float ind = (hat_s >= lo && hat_s <= hi) ? 1.f : 0.f;

        float cnt    = ws[0];
        float kde_tr = t_tr * (1.0f / (NTR * KDE_NORM));
        float kde_te = t_te * (1.0f / (NTE * KDE_NORM));
        float kw     = t_w / (fmaxf(cnt, 1.0f) * KDE_NORM);
        float p_y    = cnt * (1.0f / BSZ);
        float p_hs   = kw * p_y / (kde_tr + 1e-8f);
        p_hs = fminf(fmaxf(p_hs, 0.f), 1.f);

        c1 = p_hs * ind * kde_te;
        c2 = p_hs * ind * kde_tr;
    }

    for (int off = 32; off > 0; off >>= 1) {
        c1 += __shfl_down(c1, off);
        c2 += __shfl_down(c2, off);
    }
    if (lane == 0) {
        atomicAdd(&S1[bin], c1);
        atomicAdd(&S2[bin], c2);
    }
}

// ===================== FB path: R2 kernel ==================================
template <int ROUNDS, bool WEIGHTED>
__device__ __forceinline__ float kde_phase_fb(const float2* __restrict__ pts,
                                              int Nq, float4* tile,
                                              const float* __restrict__ w,
                                              int tid, int wid,
                                              float qx, float qy, float qe)
{
    float acc = 0.f;
    for (int r = 0; r < ROUNDS; ++r) {
        __syncthreads();
        int off = r * FTILE + tid;
#pragma unroll
        for (int s = 0; s < 4; ++s) {
            float4 v;
            if (off < Nq) {
                float2 p = pts[s * Nq + off];
                v.x = TWO_EXPC * p.x;
                v.y = TWO_EXPC * p.y;
                v.z = -EXPC * fmaf(p.x, p.x, p.y * p.y);
                v.w = WEIGHTED ? w[s * Nq + off] : 0.f;
            } else {
                v = make_float4(0.f, 0.f, -1e30f, 0.f);
            }
            tile[s * FTILE + tid] = v;
        }
        __syncthreads();
        const float4* t4 = &tile[wid * FTILE];
#pragma unroll 8
        for (int j = 0; j < FTILE; ++j) {
            float4 v = t4[j];
            float e = fmaf(qx, v.x, fmaf(qy, v.y, v.z)) + qe;
            float k = fast_exp2(e);
            acc = WEIGHTED ? fmaf(v.w, k, acc) : (acc + k);
        }
    }
    return acc;
}

__global__ __launch_bounds__(256) void ec_kde_fb(
    const float2* __restrict__ mc2, const float2* __restrict__ train2,
    const float2* __restrict__ test2, const float2* __restrict__ batch2,
    const float* __restrict__ Wm, const float* __restrict__ bv,
    const float* __restrict__ ws, float* __restrict__ S1, float* __restrict__ S2)
{
    __shared__ float4 tile[4 * FTILE];
    __shared__ float  red[3][256];

    int tid  = threadIdx.x;
    int wid  = tid >> 6;
    int lane = tid & 63;
    int bin  = blockIdx.y;
    int m    = blockIdx.x * 64 + lane;
    int mm   = (m < NMC) ? m : (NMC - 1);

    float2 q = mc2[bin * NMC + mm];
    float qx = q.x, qy = q.y;
    float qe = -EXPC * fmaf(qx, qx, qy * qy);

    float s_tr = kde_phase_fb<20, false>(train2, NTR / 4, tile, nullptr, tid, wid, qx, qy, qe);
    float s_te = kde_phase_fb<10, false>(test2,  NTE / 4, tile, nullptr, tid, wid, qx, qy, qe);
    float s_w  = kde_phase_fb<1,  true >(batch2, BSZ / 4, tile, ws + CW_OFF, tid, wid, qx, qy, qe);

    red[0][tid] = s_tr; red[1][tid] = s_te; red[2][tid] = s_w;
    __syncthreads();

    if (tid < 64) {
        float t_tr = ((red[0][tid] + red[0][tid + 64]) + (red[0][tid + 128] + red[0][tid + 192]));
        float t_te = ((red[1][tid] + red[1][tid + 64]) + (red[1][tid + 128] + red[1][tid + 192]));
        float t_w  = ((red[2][tid] + red[2][tid + 64]) + (red[2][tid + 128] + red[2][tid + 192]));

        float lmax = -1e30f;
        float l[NCLS];
#pragma unroll
        for (int c = 0; c < NCLS; ++c) {
            l[c] = fmaf(qx, Wm[c], fmaf(qy, Wm[NCLS + c], bv[c]));
            lmax = fmaxf(lmax, l[c]);
        }
        float sume = 0.f;
#pragma unroll
        for (int c = 0; c < NCLS; ++c) sume += expf(l[c] - lmax);
        float hat_s = 1.0f / sume;

        const float step = 1.0f / 15.0f;
        float lo = bin * step;
        float hi = (bin == NB - 1) ? 1.0f : (bin + 1) * step;
        float ind = (hat_s >= lo && hat_s <= hi) ? 1.f : 0.f;

        float cnt    = ws[0];
        float kde_tr = t_tr * (1.0f / (NTR * KDE_NORM));
        float kde_te = t_te * (1.0f / (NTE * KDE_NORM));
        float kw     = t_w / (fmaxf(cnt, 1.0f) * KDE_NORM);
        float p_y    = cnt * (1.0f / BSZ);
        float p_hs   = kw * p_y / (kde_tr + 1e-8f);
        p_hs = fminf(fmaxf(p_hs, 0.f), 1.f);

        bool valid = (m < NMC);
        float c1 = valid ? p_hs * ind * kde_te : 0.f;
        float c2 = valid ? p_hs * ind * kde_tr : 0.f;

        for (int off = 32; off > 0; off >>= 1) {
            c1 += __shfl_down(c1, off);
            c2 += __shfl_down(c2, off);
        }
        if (lane == 0) {
            atomicAdd(&S1[bin], c1);
            atomicAdd(&S2[bin], c2);
        }
    }
}

// ---------------------------------------------------------------- final ----
__global__ void final_k(const float* __restrict__ ws, float* __restrict__ out)
{
    if (threadIdx.x == 0 && blockIdx.x == 0) {
        float ec = 0.f;
        for (int b = 0; b < NB; ++b) {
            float tr_rate = ws[1  + b] * (1.0f / NTR);
            float te_rate = ws[16 + b] * (1.0f / NTE);
            float s1 = ws[32 + b];
            float s2 = ws[48 + b];
            float a_te = (te_rate > 0.f) ? (1.0f / te_rate) : 0.f;
            float a_tr = (tr_rate > 0.f) ? (1.0f / tr_rate) : 0.f;
            float integral = (a_te * s1 - a_tr * s2) * (1.0f / NMC) * 100.0f;
            if (te_rate > 0.f) ec += te_rate * fabsf(integral);
        }
        out[0] = ec;
    }
}

// --------------------------------------------------------------- launch ----
extern "C" void kernel_launch(void* const* d_in, const int* in_sizes, int n_in,
                              void* d_out, int out_size, void* d_ws, size_t ws_size,
                              hipStream_t stream)
{
    const float* batch_x = (const float*)d_in[0];
    const int*   by      = (const int*)  d_in[1];
    const int*   bp      = (const int*)  d_in[2];
    const float* trp     = (const float*)d_in[3];
    const float* tep     = (const float*)d_in[4];
    const float* train_x = (const float*)d_in[5];
    const float* test_x  = (const float*)d_in[6];
    const float* Wm      = (const float*)d_in[7];
    const float* bv      = (const float*)d_in[8];
    const float* mc      = (const float*)d_in[9];

    float* ws  = (float*)d_ws;
    float* out = (float*)d_out;

    if (ws_size >= (size_t)PR_NEED) {
        // ---------------- pruned path ----------------
        hipMemsetAsync(d_ws, 0, (size_t)PR_ZERO_FLOATS * sizeof(float), stream);

        setup_k<<<(NTR + 255) / 256, 256, 0, stream>>>(by, bp, trp, tep, ws, 0);

        int*    W   = (int*)d_ws;
        float4* mcS = (float4*)((char*)d_ws + MCS_B);
        float4* trS = (float4*)((char*)d_ws + TRS_B);
        float4* teS = (float4*)((char*)d_ws + TES_B);
        float4* bxS = (float4*)((char*)d_ws + BXS_B);

        count_k<<<(NQ_ALL + 255) / 256, 256, 0, stream>>>(
            (const float2*)batch_x, (const float2*)train_x,
            (const float2*)test_x, (const float2*)mc, W);

        scan_k<<<1, 256, 0, stream>>>(W);

        scatter_k<<<(NQ_ALL + 255) / 256, 256, 0, stream>>>(
            (const float2*)batch_x, by, bp,
            (const float2*)train_x, (const float2*)test_x, (const float2*)mc,
            W, bxS, trS, teS, mcS);

        dim3 grid(NCELL, QCH, SLICES);
        main_k<<<grid, 256, 0, stream>>>(W, mcS, trS, teS, bxS, ws + P_PR);

        combine_pr<<<(NQ_ALL + 2047) / 2048, 1024, 0, stream>>>(
            mcS, Wm, bv, ws, ws + P_PR, ws + 32, ws + 48);
    } else if (ws_size >= (size_t)WS_MID_FLOATS * sizeof(float)) {
        // ---------------- mid path (R5) ----------------
        hipMemsetAsync(d_ws, 0, (size_t)WS_MID_FLOATS * sizeof(float), stream);

        setup_k<<<(NTR + 255) / 256, 256, 0, stream>>>(by, bp, trp, tep, ws, 1);

        dim3 gA((NMC + 256 * MMQ - 1) / (256 * MMQ), NB, MDS);
        kdeA_mid<<<gA, 256, 0, stream>>>(
            (const float2*)mc, (const float2*)train_x, (const float2*)test_x,
            (const float2*)batch_x, ws, ws + P_MID);

        dim3 gB((NMC + 255) / 256, NB);
        combine_mid<<<gB, 256, 0, stream>>>(
            (const float2*)mc, Wm, bv, ws, ws + P_MID, ws + 32, ws + 48);
    } else {
        // ---------------- fallback ----------------
        hipMemsetAsync(d_ws, 0, WS_SMALL * sizeof(float), stream);

        setup_k<<<(NTR + 255) / 256, 256, 0, stream>>>(by, bp, trp, tep, ws, 1);

        dim3 grid((NMC + 63) / 64, NB);
        ec_kde_fb<<<grid, 256, 0, stream>>>(
            (const float2*)mc,
            (const float2*)train_x, (const float2*)test_x, (const float2*)batch_x,
            Wm, bv, ws, ws + 32, ws + 48);
    }

    final_k<<<1, 64, 0, stream>>>(ws, out);
}

// Round 10
// 416.424 us; speedup vs baseline: 1.8784x; 1.8784x over previous
//
#include <hip/hip_runtime.h>
#include <hip/hip_bf16.h>

#define NB    15
#define NMC   10000
#define NTR   20000
#define NTE   10000
#define BSZ   1024
#define NCLS  10
#define NQ_ALL (NB * NMC)

// KDE constants: BW=0.3, KDE_NORM = 2*pi*BW*BW
#define KDE_NORM  0.5654866776461628f
#define EXPC      8.014972449383130f    /* log2(e)/0.18 */
#define TWO_EXPC  16.029944898766260f   /* 2*EXPC */
#define LOG2E     1.4426950408889634f

// spatial grid: 12x12 unit cells over [-6,6]^2. 5x5 box => dropped pairs have
// gap >= 2.0 -> k <= exp(-22.2) = 2.2e-10; error ~1e-8 after norm.
#define GX      12
#define NCELL   144
#define CELL_LO -6.0f

// ---------------- pruned-path ws layout -----------------------------------
#define MC_ST  64
#define TR_ST  224
#define TE_ST  384
#define BX_ST  544
#define MC_CUR 704
#define TR_CUR 864
#define TE_CUR 1024
#define BX_CUR 1184
#define P_PR   1344
#define PR_ZERO_FLOATS (P_PR + 3 * NQ_ALL)
#define MCS_B   (PR_ZERO_FLOATS * 4)
#define TRS_B   (MCS_B + NQ_ALL * 16)
#define TES_B   (TRS_B + NTR * 16)
#define BXS_B   (TES_B + NTE * 16)
#define PR_NEED (BXS_B + BSZ * 16)

#define QCH    7       /* q-chunks of 256 (R8-winning config) */
#define SLICES 8       /* data slices for tr/te; batch on slice 0 */

// ---------------- mid-path (R5) layout ------------------------------------
#define CW_OFF   64
#define P_MID    1088
#define WS_MID_FLOATS (P_MID + 3 * NQ_ALL)
#define MDS   17
#define MTILE 256
#define MMQ   8

// ---------------- fallback path -------------------------------------------
#define WS_SMALL 1088
#define FTILE 256

typedef float v2f __attribute__((ext_vector_type(2)));

__device__ __forceinline__ float fast_exp2(float x) {
#if __has_builtin(__builtin_amdgcn_exp2f)
    return __builtin_amdgcn_exp2f(x);
#else
    return exp2f(x);
#endif
}

__device__ __forceinline__ int cell_of(float x, float y) {
    int ix = (int)floorf(x - CELL_LO);
    ix = min(max(ix, 0), GX - 1);
    int iy = (int)floorf(y - CELL_LO);
    iy = min(max(iy, 0), GX - 1);
    return iy * GX + ix;
}

// ---------------------------------------------------------------- setup ----
__global__ void setup_k(const int* __restrict__ by, const int* __restrict__ bp,
                        const float* __restrict__ trp, const float* __restrict__ tep,
                        float* __restrict__ ws, int write_cw)
{
    int i    = blockIdx.x * blockDim.x + threadIdx.x;
    int lane = threadIdx.x & 63;

    float c = 0.f;
    if (i < BSZ) {
        c = (by[i] == bp[i]) ? 1.f : 0.f;
        if (write_cw) ws[CW_OFF + i] = c;
    }
    unsigned long long mc = __ballot(c != 0.f);
    if (lane == 0 && mc) atomicAdd(&ws[0], (float)__popcll(mc));

    float p_tr = (i < NTR) ? trp[i] : -1.f;
    float p_te = (i < NTE) ? tep[i] : -1.f;
    const float step = 1.0f / 15.0f;
    for (int b2 = 0; b2 < NB; b2++) {
        float lo = b2 * step;
        float hi = (b2 == NB - 1) ? 1.0f : (b2 + 1) * step;
        unsigned long long m1 = __ballot(p_tr > lo && p_tr <= hi);
        unsigned long long m2 = __ballot(p_te > lo && p_te <= hi);
        if (lane == 0) {
            if (m1) atomicAdd(&ws[1  + b2], (float)__popcll(m1));
            if (m2) atomicAdd(&ws[16 + b2], (float)__popcll(m2));
        }
    }
}

// ------------------------------------------------- privatized count sort ---
// R9 post-mortem: count_k/scatter_k hammered 144 words with 150k device-scope
// atomics (~1000 serialized cross-XCD ops per word ~ 250-300us combined).
// Fix: per-block LDS histogram; ONE global atomic per touched cell per block.
__global__ __launch_bounds__(1024) void count_priv(
    const float2* __restrict__ mc, const float2* __restrict__ tr,
    const float2* __restrict__ te, const float2* __restrict__ bx,
    int* __restrict__ W)
{
    __shared__ int h[NCELL];
    int ds  = blockIdx.y;
    int N   = (ds == 0) ? NQ_ALL : (ds == 1) ? NTR : (ds == 2) ? NTE : BSZ;
    if ((int)blockIdx.x * 1024 >= N) return;
    const float2* src = (ds == 0) ? mc : (ds == 1) ? tr : (ds == 2) ? te : bx;
    int st = (ds == 0) ? MC_ST : (ds == 1) ? TR_ST : (ds == 2) ? TE_ST : BX_ST;

    int tid = threadIdx.x;
    if (tid < NCELL) h[tid] = 0;
    __syncthreads();
    int i = blockIdx.x * 1024 + tid;
    if (i < N) {
        float2 p = src[i];
        atomicAdd(&h[cell_of(p.x, p.y)], 1);
    }
    __syncthreads();
    if (tid < NCELL && h[tid]) atomicAdd(&W[st + 1 + tid], h[tid]);
}

// Parallel LDS scan.
__global__ void scan_k(int* __restrict__ W)
{
    __shared__ int buf[NCELL];
    int tid = threadIdx.x;   // 256
#pragma unroll
    for (int t = 0; t < 4; ++t) {
        int st  = (t == 0) ? MC_ST  : (t == 1) ? TR_ST  : (t == 2) ? TE_ST  : BX_ST;
        int cur = (t == 0) ? MC_CUR : (t == 1) ? TR_CUR : (t == 2) ? TE_CUR : BX_CUR;
        int v = 0;
        if (tid < NCELL) { v = W[st + 1 + tid]; buf[tid] = v; }
        __syncthreads();
        for (int off = 1; off < NCELL; off <<= 1) {
            int x = 0;
            if (tid < NCELL && tid >= off) x = buf[tid - off];
            __syncthreads();
            if (tid < NCELL) buf[tid] += x;
            __syncthreads();
        }
        if (tid < NCELL) {
            int start = buf[tid] - v;          // exclusive
            W[st  + tid] = start;
            W[cur + tid] = start;
            if (tid == NCELL - 1) W[st + NCELL] = buf[tid];
        }
        __syncthreads();
    }
}

__global__ __launch_bounds__(1024) void scatter_priv(
    const float2* __restrict__ mc, const float2* __restrict__ tr,
    const float2* __restrict__ te, const float2* __restrict__ bx,
    const int* __restrict__ by, const int* __restrict__ bp,
    int* __restrict__ W,
    float4* __restrict__ mcS, float4* __restrict__ trS,
    float4* __restrict__ teS, float4* __restrict__ bxS)
{
    __shared__ int h[NCELL];
    __shared__ int base[NCELL];
    int ds  = blockIdx.y;
    int N   = (ds == 0) ? NQ_ALL : (ds == 1) ? NTR : (ds == 2) ? NTE : BSZ;
    if ((int)blockIdx.x * 1024 >= N) return;
    const float2* src = (ds == 0) ? mc : (ds == 1) ? tr : (ds == 2) ? te : bx;
    int cur = (ds == 0) ? MC_CUR : (ds == 1) ? TR_CUR : (ds == 2) ? TE_CUR : BX_CUR;

    int tid = threadIdx.x;
    if (tid < NCELL) h[tid] = 0;
    __syncthreads();

    int i = blockIdx.x * 1024 + tid;
    int cell = 0, rank = 0;
    float2 p;
    if (i < N) {
        p = src[i];
        cell = cell_of(p.x, p.y);
        rank = atomicAdd(&h[cell], 1);          // LDS atomic: local rank
    }
    __syncthreads();
    if (tid < NCELL && h[tid]) base[tid] = atomicAdd(&W[cur + tid], h[tid]);
    __syncthreads();

    if (i < N) {
        int pos = base[cell] + rank;
        if (ds == 0) {
            mcS[pos] = make_float4(p.x, p.y,
                                   -EXPC * fmaf(p.x, p.x, p.y * p.y),
                                   (float)(i / NMC));
        } else {
            float w = 1.f;
            if (ds == 3) w = (by[i] == bp[i]) ? 1.f : 0.f;
            float4 v = make_float4(TWO_EXPC * p.x, TWO_EXPC * p.y,
                                   -EXPC * fmaf(p.x, p.x, p.y * p.y), w);
            if (ds == 1) trS[pos] = v;
            else if (ds == 2) teS[pos] = v;
            else bxS[pos] = v;
        }
    }
}

// ------------------------------------------------------------- main KDE ----
// R8-winning shape: block = (cell, q-chunk-of-256, slice); 1 q per thread;
// batch dataset on slice 0 only. Staged 256-point LDS tiles, broadcast reads.
__global__ __launch_bounds__(256) void main_k(
    const int*    __restrict__ W,
    const float4* __restrict__ mcS,
    const float4* __restrict__ trS,
    const float4* __restrict__ teS,
    const float4* __restrict__ bxS,
    float* __restrict__ P)
{
    __shared__ float4 tile[256];

    int tid   = threadIdx.x;
    int cell  = blockIdx.x;
    int chunk = blockIdx.y;
    int slice = blockIdx.z;

    int qs   = W[MC_ST + cell];
    int qend = W[MC_ST + cell + 1];
    int ci = cell % GX, cj = cell / GX;
    int dj0 = max(cj - 2, 0), dj1 = min(cj + 2, GX - 1);
    int di0 = max(ci - 2, 0), di1 = min(ci + 2, GX - 1);

    for (int q0 = qs + chunk * 256; q0 < qend; q0 += QCH * 256) {
        int  qidx  = q0 + tid;
        bool valid = qidx < qend;
        float4 q4 = mcS[valid ? qidx : qs];
        float qx = q4.x, qy = q4.y, qe = q4.z;

        float a0 = 0.f, a1 = 0.f, a2 = 0.f;
#pragma unroll
        for (int ds = 0; ds < 3; ++ds) {
            if (ds == 2 && slice != 0) continue;        // batch: slice 0 only
            const float4* D  = (ds == 0) ? trS : ((ds == 1) ? teS : bxS);
            const int*    St = W + ((ds == 0) ? TR_ST : ((ds == 1) ? TE_ST : BX_ST));
            int ns = (ds == 2) ? 1 : SLICES;
            int sl = (ds == 2) ? 0 : slice;

            float accl = 0.f;
            for (int dj = dj0; dj <= dj1; ++dj) {
                int s0  = St[dj * GX + di0];
                int s1  = St[dj * GX + di1 + 1];
                int len = s1 - s0;
                int ss  = s0 + (len * sl) / ns;
                int se  = s0 + (len * (sl + 1)) / ns;
                for (int t0 = ss; t0 < se; t0 += 256) {
                    __syncthreads();
                    int o = t0 + tid;
                    tile[tid] = (o < se) ? D[o]
                                         : make_float4(0.f, 0.f, -1e30f, 0.f);
                    __syncthreads();
                    int cnt = min(256, se - t0);
#pragma unroll 4
                    for (int j = 0; j < cnt; ++j) {
                        float4 d = tile[j];
                        float e = fmaf(qx, d.x, fmaf(qy, d.y, d.z + qe));
                        accl = fmaf(d.w, fast_exp2(e), accl);
                    }
                }
            }
            if (ds == 0) a0 = accl; else if (ds == 1) a1 = accl; else a2 = accl;
        }

        if (valid) {
            atomicAdd(&P[qidx], a0);
            atomicAdd(&P[NQ_ALL + qidx], a1);
            if (slice == 0) atomicAdd(&P[2 * NQ_ALL + qidx], a2);
        }
        __syncthreads();
    }
}

// ------------------------------------------------------------- combine ----
__global__ __launch_bounds__(1024) void combine_pr(
    const float4* __restrict__ mcS,
    const float*  __restrict__ Wm,
    const float*  __restrict__ bv,
    const float*  __restrict__ wsf,   // [0] = cnt
    const float*  __restrict__ P,
    float* __restrict__ S1, float* __restrict__ S2)
{
    __shared__ float sb1[NB], sb2[NB];
    int tid = threadIdx.x;
    if (tid < NB) { sb1[tid] = 0.f; sb2[tid] = 0.f; }
    __syncthreads();

#pragma unroll
    for (int rep = 0; rep < 2; ++rep) {
        int i = blockIdx.x * 2048 + rep * 1024 + tid;
        if (i < NQ_ALL) {
            float4 q4 = mcS[i];
            float qx = q4.x, qy = q4.y;
            int bin = (int)q4.w;
            float t_tr = P[i];
            float t_te = P[NQ_ALL + i];
            float t_w  = P[2 * NQ_ALL + i];

            float lmax = -1e30f;
            float l[NCLS];
#pragma unroll
            for (int c = 0; c < NCLS; ++c) {
                l[c] = fmaf(qx, Wm[c], fmaf(qy, Wm[NCLS + c], bv[c]));
                lmax = fmaxf(lmax, l[c]);
            }
            float sume = 0.f;
#pragma unroll
            for (int c = 0; c < NCLS; ++c) sume += fast_exp2((l[c] - lmax) * LOG2E);
            float hat_s = 1.0f / sume;

            const float step = 1.0f / 15.0f;
            float lo = bin * step;
            float hi = (bin == NB - 1) ? 1.0f : (bin + 1) * step;
            float ind = (hat_s >= lo && hat_s <= hi) ? 1.f : 0.f;

            float cnt    = wsf[0];
            float kde_tr = t_tr * (1.0f / (NTR * KDE_NORM));
            float kde_te = t_te * (1.0f / (NTE * KDE_NORM));
            float kw     = t_w / (fmaxf(cnt, 1.0f) * KDE_NORM);
            float p_y    = cnt * (1.0f / BSZ);
            float p_hs   = kw * p_y / (kde_tr + 1e-8f);
            p_hs = fminf(fmaxf(p_hs, 0.f), 1.f);

            float c1 = p_hs * ind * kde_te;
            float c2 = p_hs * ind * kde_tr;
            if (c1 != 0.f) atomicAdd(&sb1[bin], c1);
            if (c2 != 0.f) atomicAdd(&sb2[bin], c2);
        }
    }
    __syncthreads();
    if (tid < NB) {
        if (sb1[tid] != 0.f) atomicAdd(&S1[tid], sb1[tid]);
        if (sb2[tid] != 0.f) atomicAdd(&S2[tid], sb2[tid]);
    }
}

// ===================== MID path: R5 kernel =================================
template <bool W>
__device__ __forceinline__ void mid_phase(const float2* __restrict__ pts,
                                          const float* __restrict__ wgt,
                                          int N, int slice,
                                          float* sAB, float* sCW,
                                          const float* qx, const float* qy, const float* qe,
                                          v2f* acc, int tid)
{
    v2f qx2[MMQ], qy2[MMQ], qe2[MMQ];
#pragma unroll
    for (int k = 0; k < MMQ; ++k) {
        qx2[k] = v2f{qx[k], qx[k]};
        qy2[k] = v2f{qy[k], qy[k]};
        qe2[k] = v2f{qe[k], qe[k]};
        acc[k] = v2f{0.f, 0.f};
    }

    int L      = (N + MDS - 1) / MDS;
    int start  = slice * L;
    int len    = min(L, N - start);
    int rounds = (len + MTILE - 1) / MTILE;
    for (int r = 0; r < rounds; ++r) {
        __syncthreads();
        int o = r * MTILE + tid;
        float a = 0.f, b = 0.f, c = -1e30f, wv = 0.f;
        if (o < len) {
            float2 p = pts[start + o];
            a = TWO_EXPC * p.x;
            b = TWO_EXPC * p.y;
            c = -EXPC * fmaf(p.x, p.x, p.y * p.y);
            if (W) wv = wgt[start + o];
        }
        int g4 = 4 * (tid >> 1) + (tid & 1);
        sAB[g4] = a;  sAB[g4 + 2] = b;
        sCW[g4] = c;  sCW[g4 + 2] = wv;
        __syncthreads();

        int cnt = min(MTILE, len - r * MTILE);
        int ng  = (cnt + 1) >> 1;
        const float4* AB4 = (const float4*)sAB;
        const float4* CW4 = (const float4*)sCW;
        for (int g = 0; g < ng; ++g) {
            float4 AB = AB4[g];
            float4 CW = CW4[g];
            v2f a01; a01.x = AB.x; a01.y = AB.y;
            v2f b01; b01.x = AB.z; b01.y = AB.w;
            v2f c01; c01.x = CW.x; c01.y = CW.y;
            v2f w01; w01.x = CW.z; w01.y = CW.w;
#pragma unroll
            for (int k = 0; k < MMQ; ++k) {
                v2f t0, t1, e;
                asm("v_pk_add_f32 %0, %1, %2" : "=v"(t0) : "v"(c01), "v"(qe2[k]));
                asm("v_pk_fma_f32 %0, %1, %2, %3" : "=v"(t1) : "v"(b01), "v"(qy2[k]), "v"(t0));
                asm("v_pk_fma_f32 %0, %1, %2, %3" : "=v"(e) : "v"(a01), "v"(qx2[k]), "v"(t1));
                float k0 = fast_exp2(e.x);
                float k1 = fast_exp2(e.y);
                if (W) {
                    acc[k].x = fmaf(w01.x, k0, acc[k].x);
                    acc[k].y = fmaf(w01.y, k1, acc[k].y);
                } else {
                    acc[k].x += k0;
                    acc[k].y += k1;
                }
            }
        }
    }
}

__global__ __launch_bounds__(256) void kdeA_mid(
    const float2* __restrict__ mc2,
    const float2* __restrict__ tr2,
    const float2* __restrict__ te2,
    const float2* __restrict__ bx2,
    const float*  __restrict__ ws,
    float* __restrict__ P)
{
    __shared__ float sAB[2 * MTILE];
    __shared__ float sCW[2 * MTILE];

    int tid   = threadIdx.x;
    int bin   = blockIdx.y;
    int slice = blockIdx.z;
    int base  = blockIdx.x * (256 * MMQ);

    int qi[MMQ];
    float qx[MMQ], qy[MMQ], qe[MMQ];
#pragma unroll
    for (int k = 0; k < MMQ; ++k) {
        qi[k] = base + k * 256 + tid;
        int qs = qi[k] < NMC ? qi[k] : (NMC - 1);
        float2 q = mc2[bin * NMC + qs];
        qx[k] = q.x;
        qy[k] = q.y;
        qe[k] = -EXPC * fmaf(q.x, q.x, q.y * q.y);
    }

    v2f acc[MMQ];

    mid_phase<false>(tr2, nullptr, NTR, slice, sAB, sCW, qx, qy, qe, acc, tid);
#pragma unroll
    for (int k = 0; k < MMQ; ++k)
        if (qi[k] < NMC) atomicAdd(&P[bin * NMC + qi[k]], acc[k].x + acc[k].y);

    mid_phase<false>(te2, nullptr, NTE, slice, sAB, sCW, qx, qy, qe, acc, tid);
#pragma unroll
    for (int k = 0; k < MMQ; ++k)
        if (qi[k] < NMC) atomicAdd(&P[NQ_ALL + bin * NMC + qi[k]], acc[k].x + acc[k].y);

    mid_phase<true>(bx2, ws + CW_OFF, BSZ, slice, sAB, sCW, qx, qy, qe, acc, tid);
#pragma unroll
    for (int k = 0; k < MMQ; ++k)
        if (qi[k] < NMC) atomicAdd(&P[2 * NQ_ALL + bin * NMC + qi[k]], acc[k].x + acc[k].y);
}

__global__ void combine_mid(const float2* __restrict__ mc2,
                            const float*  __restrict__ Wm,
                            const float*  __restrict__ bv,
                            const float*  __restrict__ ws,
                            const float*  __restrict__ P,
                            float* __restrict__ S1, float* __restrict__ S2)
{
    int bin  = blockIdx.y;
    int m    = blockIdx.x * 256 + threadIdx.x;
    int lane = threadIdx.x & 63;

    float c1 = 0.f, c2 = 0.f;
    if (m < NMC) {
        float2 q = mc2[bin * NMC + m];
        int idx  = bin * NMC + m;
        float t_tr = P[idx];
        float t_te = P[NQ_ALL + idx];
        float t_w  = P[2 * NQ_ALL + idx];

        float lmax = -1e30f;
        float l[NCLS];
#pragma unroll
        for (int c = 0; c < NCLS; ++c) {
            l[c] = fmaf(q.x, Wm[c], fmaf(q.y, Wm[NCLS + c], bv[c]));
            lmax = fmaxf(lmax, l[c]);
        }
        float sume = 0.f;
#pragma unroll
        for (int c = 0; c < NCLS; ++c) sume += expf(l[c] - lmax);
        float hat_s = 1.0f / sume;

        const float step = 1.0f / 15.0f;
        float lo = bin * step;
        float hi = (bin == NB - 1) ? 1.0f : (bin + 1) * step;
        float ind = (hat_s >= lo && hat_s <= hi) ? 1.f : 0.f;

        float cnt    = ws[0];
        float kde_tr = t_tr * (1.0f / (NTR * KDE_NORM));
        float kde_te = t_te * (1.0f / (NTE * KDE_NORM));
        float kw     = t_w / (fmaxf(cnt, 1.0f) * KDE_NORM);
        float p_y    = cnt * (1.0f / BSZ);
        float p_hs   = kw * p_y / (kde_tr + 1e-8f);
        p_hs = fminf(fmaxf(p_hs, 0.f), 1.f);

        c1 = p_hs * ind * kde_te;
        c2 = p_hs * ind * kde_tr;
    }

    for (int off = 32; off > 0; off >>= 1) {
        c1 += __shfl_down(c1, off);
        c2 += __shfl_down(c2, off);
    }
    if (lane == 0) {
        atomicAdd(&S1[bin], c1);
        atomicAdd(&S2[bin], c2);
    }
}

// ===================== FB path: R2 kernel ==================================
template <int ROUNDS, bool WEIGHTED>
__device__ __forceinline__ float kde_phase_fb(const float2* __restrict__ pts,
                                              int Nq, float4* tile,
                                              const float* __restrict__ w,
                                              int tid, int wid,
                                              float qx, float qy, float qe)
{
    float acc = 0.f;
    for (int r = 0; r < ROUNDS; ++r) {
        __syncthreads();
        int off = r * FTILE + tid;
#pragma unroll
        for (int s = 0; s < 4; ++s) {
            float4 v;
            if (off < Nq) {
                float2 p = pts[s * Nq + off];
                v.x = TWO_EXPC * p.x;
                v.y = TWO_EXPC * p.y;
                v.z = -EXPC * fmaf(p.x, p.x, p.y * p.y);
                v.w = WEIGHTED ? w[s * Nq + off] : 0.f;
            } else {
                v = make_float4(0.f, 0.f, -1e30f, 0.f);
            }
            tile[s * FTILE + tid] = v;
        }
        __syncthreads();
        const float4* t4 = &tile[wid * FTILE];
#pragma unroll 8
        for (int j = 0; j < FTILE; ++j) {
            float4 v = t4[j];
            float e = fmaf(qx, v.x, fmaf(qy, v.y, v.z)) + qe;
            float k = fast_exp2(e);
            acc = WEIGHTED ? fmaf(v.w, k, acc) : (acc + k);
        }
    }
    return acc;
}

__global__ __launch_bounds__(256) void ec_kde_fb(
    const float2* __restrict__ mc2, const float2* __restrict__ train2,
    const float2* __restrict__ test2, const float2* __restrict__ batch2,
    const float* __restrict__ Wm, const float* __restrict__ bv,
    const float* __restrict__ ws, float* __restrict__ S1, float* __restrict__ S2)
{
    __shared__ float4 tile[4 * FTILE];
    __shared__ float  red[3][256];

    int tid  = threadIdx.x;
    int wid  = tid >> 6;
    int lane = tid & 63;
    int bin  = blockIdx.y;
    int m    = blockIdx.x * 64 + lane;
    int mm   = (m < NMC) ? m : (NMC - 1);

    float2 q = mc2[bin * NMC + mm];
    float qx = q.x, qy = q.y;
    float qe = -EXPC * fmaf(qx, qx, qy * qy);

    float s_tr = kde_phase_fb<20, false>(train2, NTR / 4, tile, nullptr, tid, wid, qx, qy, qe);
    float s_te = kde_phase_fb<10, false>(test2,  NTE / 4, tile, nullptr, tid, wid, qx, qy, qe);
    float s_w  = kde_phase_fb<1,  true >(batch2, BSZ / 4, tile, ws + CW_OFF, tid, wid, qx, qy, qe);

    red[0][tid] = s_tr; red[1][tid] = s_te; red[2][tid] = s_w;
    __syncthreads();

    if (tid < 64) {
        float t_tr = ((red[0][tid] + red[0][tid + 64]) + (red[0][tid + 128] + red[0][tid + 192]));
        float t_te = ((red[1][tid] + red[1][tid + 64]) + (red[1][tid + 128] + red[1][tid + 192]));
        float t_w  = ((red[2][tid] + red[2][tid + 64]) + (red[2][tid + 128] + red[2][tid + 192]));

        float lmax = -1e30f;
        float l[NCLS];
#pragma unroll
        for (int c = 0; c < NCLS; ++c) {
            l[c] = fmaf(qx, Wm[c], fmaf(qy, Wm[NCLS + c], bv[c]));
            lmax = fmaxf(lmax, l[c]);
        }
        float sume = 0.f;
#pragma unroll
        for (int c = 0; c < NCLS; ++c) sume += expf(l[c] - lmax);
        float hat_s = 1.0f / sume;

        const float step = 1.0f / 15.0f;
        float lo = bin * step;
        float hi = (bin == NB - 1) ? 1.0f : (bin + 1) * step;
        float ind = (hat_s >= lo && hat_s <= hi) ? 1.f : 0.f;

        float cnt    = ws[0];
        float kde_tr = t_tr * (1.0f / (NTR * KDE_NORM));
        float kde_te = t_te * (1.0f / (NTE * KDE_NORM));
        float kw     = t_w / (fmaxf(cnt, 1.0f) * KDE_NORM);
        float p_y    = cnt * (1.0f / BSZ);
        float p_hs   = kw * p_y / (kde_tr + 1e-8f);
        p_hs = fminf(fmaxf(p_hs, 0.f), 1.f);

        bool valid = (m < NMC);
        float c1 = valid ? p_hs * ind * kde_te : 0.f;
        float c2 = valid ? p_hs * ind * kde_tr : 0.f;

        for (int off = 32; off > 0; off >>= 1) {
            c1 += __shfl_down(c1, off);
            c2 += __shfl_down(c2, off);
        }
        if (lane == 0) {
            atomicAdd(&S1[bin], c1);
            atomicAdd(&S2[bin], c2);
        }
    }
}

// ---------------------------------------------------------------- final ----
__global__ void final_k(const float* __restrict__ ws, float* __restrict__ out)
{
    if (threadIdx.x == 0 && blockIdx.x == 0) {
        float ec = 0.f;
        for (int b = 0; b < NB; ++b) {
            float tr_rate = ws[1  + b] * (1.0f / NTR);
            float te_rate = ws[16 + b] * (1.0f / NTE);
            float s1 = ws[32 + b];
            float s2 = ws[48 + b];
            float a_te = (te_rate > 0.f) ? (1.0f / te_rate) : 0.f;
            float a_tr = (tr_rate > 0.f) ? (1.0f / tr_rate) : 0.f;
            float integral = (a_te * s1 - a_tr * s2) * (1.0f / NMC) * 100.0f;
            if (te_rate > 0.f) ec += te_rate * fabsf(integral);
        }
        out[0] = ec;
    }
}

// --------------------------------------------------------------- launch ----
extern "C" void kernel_launch(void* const* d_in, const int* in_sizes, int n_in,
                              void* d_out, int out_size, void* d_ws, size_t ws_size,
                              hipStream_t stream)
{
    const float* batch_x = (const float*)d_in[0];
    const int*   by      = (const int*)  d_in[1];
    const int*   bp      = (const int*)  d_in[2];
    const float* trp     = (const float*)d_in[3];
    const float* tep     = (const float*)d_in[4];
    const float* train_x = (const float*)d_in[5];
    const float* test_x  = (const float*)d_in[6];
    const float* Wm      = (const float*)d_in[7];
    const float* bv      = (const float*)d_in[8];
    const float* mc      = (const float*)d_in[9];

    float* ws  = (float*)d_ws;
    float* out = (float*)d_out;

    if (ws_size >= (size_t)PR_NEED) {
        // ---------------- pruned path ----------------
        hipMemsetAsync(d_ws, 0, (size_t)PR_ZERO_FLOATS * sizeof(float), stream);

        setup_k<<<(NTR + 255) / 256, 256, 0, stream>>>(by, bp, trp, tep, ws, 0);

        int*    W   = (int*)d_ws;
        float4* mcS = (float4*)((char*)d_ws + MCS_B);
        float4* trS = (float4*)((char*)d_ws + TRS_B);
        float4* teS = (float4*)((char*)d_ws + TES_B);
        float4* bxS = (float4*)((char*)d_ws + BXS_B);

        dim3 gcnt((NQ_ALL + 1023) / 1024, 4);
        count_priv<<<gcnt, 1024, 0, stream>>>(
            (const float2*)mc, (const float2*)train_x,
            (const float2*)test_x, (const float2*)batch_x, W);

        scan_k<<<1, 256, 0, stream>>>(W);

        scatter_priv<<<gcnt, 1024, 0, stream>>>(
            (const float2*)mc, (const float2*)train_x,
            (const float2*)test_x, (const float2*)batch_x,
            by, bp, W, mcS, trS, teS, bxS);

        dim3 grid(NCELL, QCH, SLICES);
        main_k<<<grid, 256, 0, stream>>>(W, mcS, trS, teS, bxS, ws + P_PR);

        combine_pr<<<(NQ_ALL + 2047) / 2048, 1024, 0, stream>>>(
            mcS, Wm, bv, ws, ws + P_PR, ws + 32, ws + 48);
    } else if (ws_size >= (size_t)WS_MID_FLOATS * sizeof(float)) {
        // ---------------- mid path (R5) ----------------
        hipMemsetAsync(d_ws, 0, (size_t)WS_MID_FLOATS * sizeof(float), stream);

        setup_k<<<(NTR + 255) / 256, 256, 0, stream>>>(by, bp, trp, tep, ws, 1);

        dim3 gA((NMC + 256 * MMQ - 1) / (256 * MMQ), NB, MDS);
        kdeA_mid<<<gA, 256, 0, stream>>>(
            (const float2*)mc, (const float2*)train_x, (const float2*)test_x,
            (const float2*)batch_x, ws, ws + P_MID);

        dim3 gB((NMC + 255) / 256, NB);
        combine_mid<<<gB, 256, 0, stream>>>(
            (const float2*)mc, Wm, bv, ws, ws + P_MID, ws + 32, ws + 48);
    } else {
        // ---------------- fallback ----------------
        hipMemsetAsync(d_ws, 0, WS_SMALL * sizeof(float), stream);

        setup_k<<<(NTR + 255) / 256, 256, 0, stream>>>(by, bp, trp, tep, ws, 1);

        dim3 grid((NMC + 63) / 64, NB);
        ec_kde_fb<<<grid, 256, 0, stream>>>(
            (const float2*)mc,
            (const float2*)train_x, (const float2*)test_x, (const float2*)batch_x,
            Wm, bv, ws, ws + 32, ws + 48);
    }

    final_k<<<1, 64, 0, stream>>>(ws, out);
}

// Round 11
// 381.763 us; speedup vs baseline: 2.0489x; 1.0908x over previous
//
#include <hip/hip_runtime.h>
#include <hip/hip_bf16.h>

#define NB    15
#define NMC   10000
#define NTR   20000
#define NTE   10000
#define BSZ   1024
#define NCLS  10
#define NQ_ALL (NB * NMC)

// KDE constants: BW=0.3, KDE_NORM = 2*pi*BW*BW
#define KDE_NORM  0.5654866776461628f
#define EXPC      8.014972449383130f    /* log2(e)/0.18 */
#define TWO_EXPC  16.029944898766260f   /* 2*EXPC */
#define LOG2E     1.4426950408889634f

// spatial grid: 12x12 unit cells over [-6,6]^2. 5x5 box => dropped pairs have
// gap >= 2.0 -> k <= exp(-22.2) = 2.2e-10; error ~1e-8 after norm.
#define GX      12
#define NCELL   144
#define CELL_LO -6.0f

// ---------------- pruned-path ws layout -----------------------------------
#define MC_ST  64
#define TR_ST  224
#define TE_ST  384
#define BX_ST  544
#define MC_CUR 704
#define TR_CUR 864
#define TE_CUR 1024
#define BX_CUR 1184
#define P_PR   1344
#define PR_ZERO_FLOATS (P_PR + 3 * NQ_ALL)
#define MCS_B   (PR_ZERO_FLOATS * 4)
#define TRS_B   (MCS_B + NQ_ALL * 16)
#define TES_B   (TRS_B + NTR * 16)
#define BXS_B   (TES_B + NTE * 16)
#define PR_NEED (BXS_B + BSZ * 16)

#define QCH    7       /* q-chunks of 256 (R8-winning config) */
#define SLICES 16      /* finer tr/te slicing for tail balance (R10: 70% VALUBusy) */

// ---------------- mid-path (R5) layout ------------------------------------
#define CW_OFF   64
#define P_MID    1088
#define WS_MID_FLOATS (P_MID + 3 * NQ_ALL)
#define MDS   17
#define MTILE 256
#define MMQ   8

// ---------------- fallback path -------------------------------------------
#define WS_SMALL 1088
#define FTILE 256

typedef float v2f __attribute__((ext_vector_type(2)));

__device__ __forceinline__ float fast_exp2(float x) {
#if __has_builtin(__builtin_amdgcn_exp2f)
    return __builtin_amdgcn_exp2f(x);
#else
    return exp2f(x);
#endif
}

__device__ __forceinline__ int cell_of(float x, float y) {
    int ix = (int)floorf(x - CELL_LO);
    ix = min(max(ix, 0), GX - 1);
    int iy = (int)floorf(y - CELL_LO);
    iy = min(max(iy, 0), GX - 1);
    return iy * GX + ix;
}

// -------------------------------------------- fused setup + count ----------
// One pass: correct-count, prob histograms, and per-block LDS cell histograms
// for all 4 datasets (one global atomic per touched cell per block).
__global__ __launch_bounds__(1024) void setup_count_k(
    const int* __restrict__ by, const int* __restrict__ bp,
    const float* __restrict__ trp, const float* __restrict__ tep,
    const float2* __restrict__ mc, const float2* __restrict__ tr,
    const float2* __restrict__ te, const float2* __restrict__ bx,
    float* __restrict__ ws, int* __restrict__ W)
{
    __shared__ int h[4][NCELL];
    int tid = threadIdx.x;
    for (int s = tid; s < 4 * NCELL; s += 1024) ((int*)h)[s] = 0;
    __syncthreads();

    int i    = blockIdx.x * 1024 + tid;
    int lane = tid & 63;

    float c = 0.f;
    if (i < BSZ) c = (by[i] == bp[i]) ? 1.f : 0.f;
    unsigned long long mcm = __ballot(c != 0.f);
    if (lane == 0 && mcm) atomicAdd(&ws[0], (float)__popcll(mcm));

    if ((int)blockIdx.x * 1024 < NTR) {     // block-uniform guard
        float p_tr = (i < NTR) ? trp[i] : -1.f;
        float p_te = (i < NTE) ? tep[i] : -1.f;
        const float step = 1.0f / 15.0f;
        for (int b2 = 0; b2 < NB; b2++) {
            float lo = b2 * step;
            float hi = (b2 == NB - 1) ? 1.0f : (b2 + 1) * step;
            unsigned long long m1 = __ballot(p_tr > lo && p_tr <= hi);
            unsigned long long m2 = __ballot(p_te > lo && p_te <= hi);
            if (lane == 0) {
                if (m1) atomicAdd(&ws[1  + b2], (float)__popcll(m1));
                if (m2) atomicAdd(&ws[16 + b2], (float)__popcll(m2));
            }
        }
    }

    if (i < NQ_ALL) { float2 p = mc[i]; atomicAdd(&h[0][cell_of(p.x, p.y)], 1); }
    if (i < NTR)    { float2 p = tr[i]; atomicAdd(&h[1][cell_of(p.x, p.y)], 1); }
    if (i < NTE)    { float2 p = te[i]; atomicAdd(&h[2][cell_of(p.x, p.y)], 1); }
    if (i < BSZ)    { float2 p = bx[i]; atomicAdd(&h[3][cell_of(p.x, p.y)], 1); }
    __syncthreads();

    for (int s = tid; s < 4 * NCELL; s += 1024) {
        int v = ((int*)h)[s];
        if (v) {
            int ds   = s / NCELL;
            int cell = s % NCELL;
            int st   = (ds == 0) ? MC_ST : (ds == 1) ? TR_ST : (ds == 2) ? TE_ST : BX_ST;
            atomicAdd(&W[st + 1 + cell], v);
        }
    }
}

// Parallel LDS scan.
__global__ void scan_k(int* __restrict__ W)
{
    __shared__ int buf[NCELL];
    int tid = threadIdx.x;   // 256
#pragma unroll
    for (int t = 0; t < 4; ++t) {
        int st  = (t == 0) ? MC_ST  : (t == 1) ? TR_ST  : (t == 2) ? TE_ST  : BX_ST;
        int cur = (t == 0) ? MC_CUR : (t == 1) ? TR_CUR : (t == 2) ? TE_CUR : BX_CUR;
        int v = 0;
        if (tid < NCELL) { v = W[st + 1 + tid]; buf[tid] = v; }
        __syncthreads();
        for (int off = 1; off < NCELL; off <<= 1) {
            int x = 0;
            if (tid < NCELL && tid >= off) x = buf[tid - off];
            __syncthreads();
            if (tid < NCELL) buf[tid] += x;
            __syncthreads();
        }
        if (tid < NCELL) {
            int start = buf[tid] - v;          // exclusive
            W[st  + tid] = start;
            W[cur + tid] = start;
            if (tid == NCELL - 1) W[st + NCELL] = buf[tid];
        }
        __syncthreads();
    }
}

__global__ __launch_bounds__(1024) void scatter_priv(
    const float2* __restrict__ mc, const float2* __restrict__ tr,
    const float2* __restrict__ te, const float2* __restrict__ bx,
    const int* __restrict__ by, const int* __restrict__ bp,
    int* __restrict__ W,
    float4* __restrict__ mcS, float4* __restrict__ trS,
    float4* __restrict__ teS, float4* __restrict__ bxS)
{
    __shared__ int h[NCELL];
    __shared__ int base[NCELL];
    int ds  = blockIdx.y;
    int N   = (ds == 0) ? NQ_ALL : (ds == 1) ? NTR : (ds == 2) ? NTE : BSZ;
    if ((int)blockIdx.x * 1024 >= N) return;
    const float2* src = (ds == 0) ? mc : (ds == 1) ? tr : (ds == 2) ? te : bx;
    int cur = (ds == 0) ? MC_CUR : (ds == 1) ? TR_CUR : (ds == 2) ? TE_CUR : BX_CUR;

    int tid = threadIdx.x;
    if (tid < NCELL) h[tid] = 0;
    __syncthreads();

    int i = blockIdx.x * 1024 + tid;
    int cell = 0, rank = 0;
    float2 p;
    if (i < N) {
        p = src[i];
        cell = cell_of(p.x, p.y);
        rank = atomicAdd(&h[cell], 1);          // LDS atomic: local rank
    }
    __syncthreads();
    if (tid < NCELL && h[tid]) base[tid] = atomicAdd(&W[cur + tid], h[tid]);
    __syncthreads();

    if (i < N) {
        int pos = base[cell] + rank;
        if (ds == 0) {
            mcS[pos] = make_float4(p.x, p.y,
                                   -EXPC * fmaf(p.x, p.x, p.y * p.y),
                                   (float)(i / NMC));
        } else {
            float w = 1.f;
            if (ds == 3) w = (by[i] == bp[i]) ? 1.f : 0.f;
            float4 v = make_float4(TWO_EXPC * p.x, TWO_EXPC * p.y,
                                   -EXPC * fmaf(p.x, p.x, p.y * p.y), w);
            if (ds == 1) trS[pos] = v;
            else if (ds == 2) teS[pos] = v;
            else bxS[pos] = v;
        }
    }
}

// ------------------------------------------------------------- main KDE ----
// R8-winning shape: block = (cell, q-chunk-of-256, slice); 1 q per thread;
// batch dataset on slice 0 only. Staged 256-point LDS tiles, broadcast reads.
// SLICES=16 for tail balance (work per block ~ qlen x boxlen, central-cell
// dominated; R10 showed 70% VALUBusy = ~90us tail at SLICES=8).
__global__ __launch_bounds__(256) void main_k(
    const int*    __restrict__ W,
    const float4* __restrict__ mcS,
    const float4* __restrict__ trS,
    const float4* __restrict__ teS,
    const float4* __restrict__ bxS,
    float* __restrict__ P)
{
    __shared__ float4 tile[256];

    int tid   = threadIdx.x;
    int cell  = blockIdx.x;
    int chunk = blockIdx.y;
    int slice = blockIdx.z;

    int qs   = W[MC_ST + cell];
    int qend = W[MC_ST + cell + 1];
    int ci = cell % GX, cj = cell / GX;
    int dj0 = max(cj - 2, 0), dj1 = min(cj + 2, GX - 1);
    int di0 = max(ci - 2, 0), di1 = min(ci + 2, GX - 1);

    for (int q0 = qs + chunk * 256; q0 < qend; q0 += QCH * 256) {
        int  qidx  = q0 + tid;
        bool valid = qidx < qend;
        float4 q4 = mcS[valid ? qidx : qs];
        float qx = q4.x, qy = q4.y, qe = q4.z;

        float a0 = 0.f, a1 = 0.f, a2 = 0.f;
#pragma unroll
        for (int ds = 0; ds < 3; ++ds) {
            if (ds == 2 && slice != 0) continue;        // batch: slice 0 only
            const float4* D  = (ds == 0) ? trS : ((ds == 1) ? teS : bxS);
            const int*    St = W + ((ds == 0) ? TR_ST : ((ds == 1) ? TE_ST : BX_ST));
            int ns = (ds == 2) ? 1 : SLICES;
            int sl = (ds == 2) ? 0 : slice;

            float accl = 0.f;
            for (int dj = dj0; dj <= dj1; ++dj) {
                int s0  = St[dj * GX + di0];
                int s1  = St[dj * GX + di1 + 1];
                int len = s1 - s0;
                int ss  = s0 + (len * sl) / ns;
                int se  = s0 + (len * (sl + 1)) / ns;
                for (int t0 = ss; t0 < se; t0 += 256) {
                    __syncthreads();
                    int o = t0 + tid;
                    tile[tid] = (o < se) ? D[o]
                                         : make_float4(0.f, 0.f, -1e30f, 0.f);
                    __syncthreads();
                    int cnt = min(256, se - t0);
#pragma unroll 4
                    for (int j = 0; j < cnt; ++j) {
                        float4 d = tile[j];
                        float e = fmaf(qx, d.x, fmaf(qy, d.y, d.z + qe));
                        accl = fmaf(d.w, fast_exp2(e), accl);
                    }
                }
            }
            if (ds == 0) a0 = accl; else if (ds == 1) a1 = accl; else a2 = accl;
        }

        if (valid) {
            atomicAdd(&P[qidx], a0);
            atomicAdd(&P[NQ_ALL + qidx], a1);
            if (slice == 0) atomicAdd(&P[2 * NQ_ALL + qidx], a2);
        }
        __syncthreads();
    }
}

// ------------------------------------------------------------- combine ----
__global__ __launch_bounds__(1024) void combine_pr(
    const float4* __restrict__ mcS,
    const float*  __restrict__ Wm,
    const float*  __restrict__ bv,
    const float*  __restrict__ wsf,   // [0] = cnt
    const float*  __restrict__ P,
    float* __restrict__ S1, float* __restrict__ S2)
{
    __shared__ float sb1[NB], sb2[NB];
    int tid = threadIdx.x;
    if (tid < NB) { sb1[tid] = 0.f; sb2[tid] = 0.f; }
    __syncthreads();

#pragma unroll
    for (int rep = 0; rep < 2; ++rep) {
        int i = blockIdx.x * 2048 + rep * 1024 + tid;
        if (i < NQ_ALL) {
            float4 q4 = mcS[i];
            float qx = q4.x, qy = q4.y;
            int bin = (int)q4.w;
            float t_tr = P[i];
            float t_te = P[NQ_ALL + i];
            float t_w  = P[2 * NQ_ALL + i];

            float lmax = -1e30f;
            float l[NCLS];
#pragma unroll
            for (int c = 0; c < NCLS; ++c) {
                l[c] = fmaf(qx, Wm[c], fmaf(qy, Wm[NCLS + c], bv[c]));
                lmax = fmaxf(lmax, l[c]);
            }
            float sume = 0.f;
#pragma unroll
            for (int c = 0; c < NCLS; ++c) sume += fast_exp2((l[c] - lmax) * LOG2E);
            float hat_s = 1.0f / sume;

            const float step = 1.0f / 15.0f;
            float lo = bin * step;
            float hi = (bin == NB - 1) ? 1.0f : (bin + 1) * step;
            float ind = (hat_s >= lo && hat_s <= hi) ? 1.f : 0.f;

            float cnt    = wsf[0];
            float kde_tr = t_tr * (1.0f / (NTR * KDE_NORM));
            float kde_te = t_te * (1.0f / (NTE * KDE_NORM));
            float kw     = t_w / (fmaxf(cnt, 1.0f) * KDE_NORM);
            float p_y    = cnt * (1.0f / BSZ);
            float p_hs   = kw * p_y / (kde_tr + 1e-8f);
            p_hs = fminf(fmaxf(p_hs, 0.f), 1.f);

            float c1 = p_hs * ind * kde_te;
            float c2 = p_hs * ind * kde_tr;
            if (c1 != 0.f) atomicAdd(&sb1[bin], c1);
            if (c2 != 0.f) atomicAdd(&sb2[bin], c2);
        }
    }
    __syncthreads();
    if (tid < NB) {
        if (sb1[tid] != 0.f) atomicAdd(&S1[tid], sb1[tid]);
        if (sb2[tid] != 0.f) atomicAdd(&S2[tid], sb2[tid]);
    }
}

// ===================== MID path: R5 kernel =================================
template <bool W>
__device__ __forceinline__ void mid_phase(const float2* __restrict__ pts,
                                          const float* __restrict__ wgt,
                                          int N, int slice,
                                          float* sAB, float* sCW,
                                          const float* qx, const float* qy, const float* qe,
                                          v2f* acc, int tid)
{
    v2f qx2[MMQ], qy2[MMQ], qe2[MMQ];
#pragma unroll
    for (int k = 0; k < MMQ; ++k) {
        qx2[k] = v2f{qx[k], qx[k]};
        qy2[k] = v2f{qy[k], qy[k]};
        qe2[k] = v2f{qe[k], qe[k]};
        acc[k] = v2f{0.f, 0.f};
    }

    int L      = (N + MDS - 1) / MDS;
    int start  = slice * L;
    int len    = min(L, N - start);
    int rounds = (len + MTILE - 1) / MTILE;
    for (int r = 0; r < rounds; ++r) {
        __syncthreads();
        int o = r * MTILE + tid;
        float a = 0.f, b = 0.f, c = -1e30f, wv = 0.f;
        if (o < len) {
            float2 p = pts[start + o];
            a = TWO_EXPC * p.x;
            b = TWO_EXPC * p.y;
            c = -EXPC * fmaf(p.x, p.x, p.y * p.y);
            if (W) wv = wgt[start + o];
        }
        int g4 = 4 * (tid >> 1) + (tid & 1);
        sAB[g4] = a;  sAB[g4 + 2] = b;
        sCW[g4] = c;  sCW[g4 + 2] = wv;
        __syncthreads();

        int cnt = min(MTILE, len - r * MTILE);
        int ng  = (cnt + 1) >> 1;
        const float4* AB4 = (const float4*)sAB;
        const float4* CW4 = (const float4*)sCW;
        for (int g = 0; g < ng; ++g) {
            float4 AB = AB4[g];
            float4 CW = CW4[g];
            v2f a01; a01.x = AB.x; a01.y = AB.y;
            v2f b01; b01.x = AB.z; b01.y = AB.w;
            v2f c01; c01.x = CW.x; c01.y = CW.y;
            v2f w01; w01.x = CW.z; w01.y = CW.w;
#pragma unroll
            for (int k = 0; k < MMQ; ++k) {
                v2f t0, t1, e;
                asm("v_pk_add_f32 %0, %1, %2" : "=v"(t0) : "v"(c01), "v"(qe2[k]));
                asm("v_pk_fma_f32 %0, %1, %2, %3" : "=v"(t1) : "v"(b01), "v"(qy2[k]), "v"(t0));
                asm("v_pk_fma_f32 %0, %1, %2, %3" : "=v"(e) : "v"(a01), "v"(qx2[k]), "v"(t1));
                float k0 = fast_exp2(e.x);
                float k1 = fast_exp2(e.y);
                if (W) {
                    acc[k].x = fmaf(w01.x, k0, acc[k].x);
                    acc[k].y = fmaf(w01.y, k1, acc[k].y);
                } else {
                    acc[k].x += k0;
                    acc[k].y += k1;
                }
            }
        }
    }
}

__global__ __launch_bounds__(256) void kdeA_mid(
    const float2* __restrict__ mc2,
    const float2* __restrict__ tr2,
    const float2* __restrict__ te2,
    const float2* __restrict__ bx2,
    const float*  __restrict__ ws,
    float* __restrict__ P)
{
    __shared__ float sAB[2 * MTILE];
    __shared__ float sCW[2 * MTILE];

    int tid   = threadIdx.x;
    int bin   = blockIdx.y;
    int slice = blockIdx.z;
    int base  = blockIdx.x * (256 * MMQ);

    int qi[MMQ];
    float qx[MMQ], qy[MMQ], qe[MMQ];
#pragma unroll
    for (int k = 0; k < MMQ; ++k) {
        qi[k] = base + k * 256 + tid;
        int qs = qi[k] < NMC ? qi[k] : (NMC - 1);
        float2 q = mc2[bin * NMC + qs];
        qx[k] = q.x;
        qy[k] = q.y;
        qe[k] = -EXPC * fmaf(q.x, q.x, q.y * q.y);
    }

    v2f acc[MMQ];

    mid_phase<false>(tr2, nullptr, NTR, slice, sAB, sCW, qx, qy, qe, acc, tid);
#pragma unroll
    for (int k = 0; k < MMQ; ++k)
        if (qi[k] < NMC) atomicAdd(&P[bin * NMC + qi[k]], acc[k].x + acc[k].y);

    mid_phase<false>(te2, nullptr, NTE, slice, sAB, sCW, qx, qy, qe, acc, tid);
#pragma unroll
    for (int k = 0; k < MMQ; ++k)
        if (qi[k] < NMC) atomicAdd(&P[NQ_ALL + bin * NMC + qi[k]], acc[k].x + acc[k].y);

    mid_phase<true>(bx2, ws + CW_OFF, BSZ, slice, sAB, sCW, qx, qy, qe, acc, tid);
#pragma unroll
    for (int k = 0; k < MMQ; ++k)
        if (qi[k] < NMC) atomicAdd(&P[2 * NQ_ALL + bin * NMC + qi[k]], acc[k].x + acc[k].y);
}

__global__ void combine_mid(const float2* __restrict__ mc2,
                            const float*  __restrict__ Wm,
                            const float*  __restrict__ bv,
                            const float*  __restrict__ ws,
                            const float*  __restrict__ P,
                            float* __restrict__ S1, float* __restrict__ S2)
{
    int bin  = blockIdx.y;
    int m    = blockIdx.x * 256 + threadIdx.x;
    int lane = threadIdx.x & 63;

    float c1 = 0.f, c2 = 0.f;
    if (m < NMC) {
        float2 q = mc2[bin * NMC + m];
        int idx  = bin * NMC + m;
        float t_tr = P[idx];
        float t_te = P[NQ_ALL + idx];
        float t_w  = P[2 * NQ_ALL + idx];

        float lmax = -1e30f;
        float l[NCLS];
#pragma unroll
        for (int c = 0; c < NCLS; ++c) {
            l[c] = fmaf(q.x, Wm[c], fmaf(q.y, Wm[NCLS + c], bv[c]));
            lmax = fmaxf(lmax, l[c]);
        }
        float sume = 0.f;
#pragma unroll
        for (int c = 0; c < NCLS; ++c) sume += expf(l[c] - lmax);
        float hat_s = 1.0f / sume;

        const float step = 1.0f / 15.0f;
        float lo = bin * step;
        float hi = (bin == NB - 1) ? 1.0f : (bin + 1) * step;
        float ind = (hat_s >= lo && hat_s <= hi) ? 1.f : 0.f;

        float cnt    = ws[0];
        float kde_tr = t_tr * (1.0f / (NTR * KDE_NORM));
        float kde_te = t_te * (1.0f / (NTE * KDE_NORM));
        float kw     = t_w / (fmaxf(cnt, 1.0f) * KDE_NORM);
        float p_y    = cnt * (1.0f / BSZ);
        float p_hs   = kw * p_y / (kde_tr + 1e-8f);
        p_hs = fminf(fmaxf(p_hs, 0.f), 1.f);

        c1 = p_hs * ind * kde_te;
        c2 = p_hs * ind * kde_tr;
    }

    for (int off = 32; off > 0; off >>= 1) {
        c1 += __shfl_down(c1, off);
        c2 += __shfl_down(c2, off);
    }
    if (lane == 0) {
        atomicAdd(&S1[bin], c1);
        atomicAdd(&S2[bin], c2);
    }
}

// ===================== FB path: R2 kernel ==================================
template <int ROUNDS, bool WEIGHTED>
__device__ __forceinline__ float kde_phase_fb(const float2* __restrict__ pts,
                                              int Nq, float4* tile,
                                              const float* __restrict__ w,
                                              int tid, int wid,
                                              float qx, float qy, float qe)
{
    float acc = 0.f;
    for (int r = 0; r < ROUNDS; ++r) {
        __syncthreads();
        int off = r * FTILE + tid;
#pragma unroll
        for (int s = 0; s < 4; ++s) {
            float4 v;
            if (off < Nq) {
                float2 p = pts[s * Nq + off];
                v.x = TWO_EXPC * p.x;
                v.y = TWO_EXPC * p.y;
                v.z = -EXPC * fmaf(p.x, p.x, p.y * p.y);
                v.w = WEIGHTED ? w[s * Nq + off] : 0.f;
            } else {
                v = make_float4(0.f, 0.f, -1e30f, 0.f);
            }
            tile[s * FTILE + tid] = v;
        }
        __syncthreads();
        const float4* t4 = &tile[wid * FTILE];
#pragma unroll 8
        for (int j = 0; j < FTILE; ++j) {
            float4 v = t4[j];
            float e = fmaf(qx, v.x, fmaf(qy, v.y, v.z)) + qe;
            float k = fast_exp2(e);
            acc = WEIGHTED ? fmaf(v.w, k, acc) : (acc + k);
        }
    }
    return acc;
}

__global__ __launch_bounds__(256) void ec_kde_fb(
    const float2* __restrict__ mc2, const float2* __restrict__ train2,
    const float2* __restrict__ test2, const float2* __restrict__ batch2,
    const float* __restrict__ Wm, const float* __restrict__ bv,
    const float* __restrict__ ws, float* __restrict__ S1, float* __restrict__ S2)
{
    __shared__ float4 tile[4 * FTILE];
    __shared__ float  red[3][256];

    int tid  = threadIdx.x;
    int wid  = tid >> 6;
    int lane = tid & 63;
    int bin  = blockIdx.y;
    int m    = blockIdx.x * 64 + lane;
    int mm   = (m < NMC) ? m : (NMC - 1);

    float2 q = mc2[bin * NMC + mm];
    float qx = q.x, qy = q.y;
    float qe = -EXPC * fmaf(qx, qx, qy * qy);

    float s_tr = kde_phase_fb<20, false>(train2, NTR / 4, tile, nullptr, tid, wid, qx, qy, qe);
    float s_te = kde_phase_fb<10, false>(test2,  NTE / 4, tile, nullptr, tid, wid, qx, qy, qe);
    float s_w  = kde_phase_fb<1,  true >(batch2, BSZ / 4, tile, ws + CW_OFF, tid, wid, qx, qy, qe);

    red[0][tid] = s_tr; red[1][tid] = s_te; red[2][tid] = s_w;
    __syncthreads();

    if (tid < 64) {
        float t_tr = ((red[0][tid] + red[0][tid + 64]) + (red[0][tid + 128] + red[0][tid + 192]));
        float t_te = ((red[1][tid] + red[1][tid + 64]) + (red[1][tid + 128] + red[1][tid + 192]));
        float t_w  = ((red[2][tid] + red[2][tid + 64]) + (red[2][tid + 128] + red[2][tid + 192]));

        float lmax = -1e30f;
        float l[NCLS];
#pragma unroll
        for (int c = 0; c < NCLS; ++c) {
            l[c] = fmaf(qx, Wm[c], fmaf(qy, Wm[NCLS + c], bv[c]));
            lmax = fmaxf(lmax, l[c]);
        }
        float sume = 0.f;
#pragma unroll
        for (int c = 0; c < NCLS; ++c) sume += expf(l[c] - lmax);
        float hat_s = 1.0f / sume;

        const float step = 1.0f / 15.0f;
        float lo = bin * step;
        float hi = (bin == NB - 1) ? 1.0f : (bin + 1) * step;
        float ind = (hat_s >= lo && hat_s <= hi) ? 1.f : 0.f;

        float cnt    = ws[0];
        float kde_tr = t_tr * (1.0f / (NTR * KDE_NORM));
        float kde_te = t_te * (1.0f / (NTE * KDE_NORM));
        float kw     = t_w / (fmaxf(cnt, 1.0f) * KDE_NORM);
        float p_y    = cnt * (1.0f / BSZ);
        float p_hs   = kw * p_y / (kde_tr + 1e-8f);
        p_hs = fminf(fmaxf(p_hs, 0.f), 1.f);

        bool valid = (m < NMC);
        float c1 = valid ? p_hs * ind * kde_te : 0.f;
        float c2 = valid ? p_hs * ind * kde_tr : 0.f;

        for (int off = 32; off > 0; off >>= 1) {
            c1 += __shfl_down(c1, off);
            c2 += __shfl_down(c2, off);
        }
        if (lane == 0) {
            atomicAdd(&S1[bin], c1);
            atomicAdd(&S2[bin], c2);
        }
    }
}

// ---------------------------------------------------------------- final ----
__global__ void final_k(const float* __restrict__ ws, float* __restrict__ out)
{
    if (threadIdx.x == 0 && blockIdx.x == 0) {
        float ec = 0.f;
        for (int b = 0; b < NB; ++b) {
            float tr_rate = ws[1  + b] * (1.0f / NTR);
            float te_rate = ws[16 + b] * (1.0f / NTE);
            float s1 = ws[32 + b];
            float s2 = ws[48 + b];
            float a_te = (te_rate > 0.f) ? (1.0f / te_rate) : 0.f;
            float a_tr = (tr_rate > 0.f) ? (1.0f / tr_rate) : 0.f;
            float integral = (a_te * s1 - a_tr * s2) * (1.0f / NMC) * 100.0f;
            if (te_rate > 0.f) ec += te_rate * fabsf(integral);
        }
        out[0] = ec;
    }
}

// --------------------------------------------------------------- launch ----
extern "C" void kernel_launch(void* const* d_in, const int* in_sizes, int n_in,
                              void* d_out, int out_size, void* d_ws, size_t ws_size,
                              hipStream_t stream)
{
    const float* batch_x = (const float*)d_in[0];
    const int*   by      = (const int*)  d_in[1];
    const int*   bp      = (const int*)  d_in[2];
    const float* trp     = (const float*)d_in[3];
    const float* tep     = (const float*)d_in[4];
    const float* train_x = (const float*)d_in[5];
    const float* test_x  = (const float*)d_in[6];
    const float* Wm      = (const float*)d_in[7];
    const float* bv      = (const float*)d_in[8];
    const float* mc      = (const float*)d_in[9];

    float* ws  = (float*)d_ws;
    float* out = (float*)d_out;

    if (ws_size >= (size_t)PR_NEED) {
        // ---------------- pruned path ----------------
        hipMemsetAsync(d_ws, 0, (size_t)PR_ZERO_FLOATS * sizeof(float), stream);

        int*    W   = (int*)d_ws;
        float4* mcS = (float4*)((char*)d_ws + MCS_B);
        float4* trS = (float4*)((char*)d_ws + TRS_B);
        float4* teS = (float4*)((char*)d_ws + TES_B);
        float4* bxS = (float4*)((char*)d_ws + BXS_B);

        int nblk = (NQ_ALL + 1023) / 1024;
        setup_count_k<<<nblk, 1024, 0, stream>>>(
            by, bp, trp, tep,
            (const float2*)mc, (const float2*)train_x,
            (const float2*)test_x, (const float2*)batch_x, ws, W);

        scan_k<<<1, 256, 0, stream>>>(W);

        dim3 gsc(nblk, 4);
        scatter_priv<<<gsc, 1024, 0, stream>>>(
            (const float2*)mc, (const float2*)train_x,
            (const float2*)test_x, (const float2*)batch_x,
            by, bp, W, mcS, trS, teS, bxS);

        dim3 grid(NCELL, QCH, SLICES);
        main_k<<<grid, 256, 0, stream>>>(W, mcS, trS, teS, bxS, ws + P_PR);

        combine_pr<<<(NQ_ALL + 2047) / 2048, 1024, 0, stream>>>(
            mcS, Wm, bv, ws, ws + P_PR, ws + 32, ws + 48);
    } else if (ws_size >= (size_t)WS_MID_FLOATS * sizeof(float)) {
        // ---------------- mid path (R5) ----------------
        hipMemsetAsync(d_ws, 0, (size_t)WS_MID_FLOATS * sizeof(float), stream);

        int nthr = 256;
        // original setup kernel work is folded into setup_count_k on the
        // pruned path; mid path keeps the R5 pipeline
        {
            // reuse setup via fused kernel semantics: simple re-implementation
        }
        // setup for mid path
        // (identical to R5's setup_k)
        // ---- inline setup ----
        // use a small lambda-equivalent kernel: reuse setup_count's prob part
        // Simplest: launch setup_count_k with W pointing at scratch past P_MID?
        // Safer: dedicated setup below.
        extern __global__ void setup_mid_k(const int*, const int*, const float*,
                                           const float*, float*);
        setup_mid_k<<<(NTR + nthr - 1) / nthr, nthr, 0, stream>>>(by, bp, trp, tep, ws);

        dim3 gA((NMC + 256 * MMQ - 1) / (256 * MMQ), NB, MDS);
        kdeA_mid<<<gA, 256, 0, stream>>>(
            (const float2*)mc, (const float2*)train_x, (const float2*)test_x,
            (const float2*)batch_x, ws, ws + P_MID);

        dim3 gB((NMC + 255) / 256, NB);
        combine_mid<<<gB, 256, 0, stream>>>(
            (const float2*)mc, Wm, bv, ws, ws + P_MID, ws + 32, ws + 48);
    } else {
        // ---------------- fallback ----------------
        hipMemsetAsync(d_ws, 0, WS_SMALL * sizeof(float), stream);

        extern __global__ void setup_mid_k(const int*, const int*, const float*,
                                           const float*, float*);
        setup_mid_k<<<(NTR + 255) / 256, 256, 0, stream>>>(by, bp, trp, tep, ws);

        dim3 grid((NMC + 63) / 64, NB);
        ec_kde_fb<<<grid, 256, 0, stream>>>(
            (const float2*)mc,
            (const float2*)train_x, (const float2*)test_x, (const float2*)batch_x,
            Wm, bv, ws, ws + 32, ws + 48);
    }

    final_k<<<1, 64, 0, stream>>>(ws, out);
}

// setup for mid/fallback paths (R5's setup_k with cw write)
__global__ void setup_mid_k(const int* __restrict__ by, const int* __restrict__ bp,
                            const float* __restrict__ trp, const float* __restrict__ tep,
                            float* __restrict__ ws)
{
    int i    = blockIdx.x * blockDim.x + threadIdx.x;
    int lane = threadIdx.x & 63;

    float c = 0.f;
    if (i < BSZ) {
        c = (by[i] == bp[i]) ? 1.f : 0.f;
        ws[CW_OFF + i] = c;
    }
    unsigned long long mc = __ballot(c != 0.f);
    if (lane == 0 && mc) atomicAdd(&ws[0], (float)__popcll(mc));

    float p_tr = (i < NTR) ? trp[i] : -1.f;
    float p_te = (i < NTE) ? tep[i] : -1.f;
    const float step = 1.0f / 15.0f;
    for (int b2 = 0; b2 < NB; b2++) {
        float lo = b2 * step;
        float hi = (b2 == NB - 1) ? 1.0f : (b2 + 1) * step;
        unsigned long long m1 = __ballot(p_tr > lo && p_tr <= hi);
        unsigned long long m2 = __ballot(p_te > lo && p_te <= hi);
        if (lane == 0) {
            if (m1) atomicAdd(&ws[1  + b2], (float)__popcll(m1));
            if (m2) atomicAdd(&ws[16 + b2], (float)__popcll(m2));
        }
    }
}